// Round 3
// baseline (391.546 us; speedup 1.0000x reference)
//
#include <hip/hip_runtime.h>
#include <stdint.h>
#include <stddef.h>

typedef __bf16 bf16;
typedef __bf16 bf16x8 __attribute__((ext_vector_type(8)));
typedef float  f32x4  __attribute__((ext_vector_type(4)));

// ---------------------------------------------------------------------------
// Batched fp32 -> bf16 cast: one launch converts all float tensors into the
// bf16 arena. Each thread handles 8 elements (two float4 loads, one 16B store).
// ---------------------------------------------------------------------------
struct CastArgs {
  const float* src[17];
  bf16*        dst[17];
  int          cum[18];   // cumulative vec8 counts
};

__global__ __launch_bounds__(256) void k_cast(CastArgs a, int total8)
{
  const int g = blockIdx.x * 256 + threadIdx.x;
  if (g >= total8) return;
  int t = 0;
  while (a.cum[t + 1] <= g) ++t;       // <=17 iters, wave-coherent
  const int i = g - a.cum[t];
  const float4* s = (const float4*)(a.src[t]) + (size_t)i * 2;
  const float4 x0 = s[0], x1 = s[1];
  bf16x8 y;
  y[0] = (bf16)x0.x; y[1] = (bf16)x0.y; y[2] = (bf16)x0.z; y[3] = (bf16)x0.w;
  y[4] = (bf16)x1.x; y[5] = (bf16)x1.y; y[6] = (bf16)x1.z; y[7] = (bf16)x1.w;
  *(bf16x8*)(a.dst[t] + (size_t)i * 8) = y;
}

// ---------------------------------------------------------------------------
// GEMM: C[M,N] = A[M,K] @ B[N,K]^T + bias, optional ReLU. bf16 in/out, fp32 acc.
// 128x128 block tile, 256 threads (2x2 waves of 64x64), BK=64.
// Register-mediated staging; LDS rows padded to 72 elements.
// ---------------------------------------------------------------------------
__device__ __forceinline__ void gemm_tile_128(
    const bf16* __restrict__ A, const bf16* __restrict__ B,
    const bf16* __restrict__ bias, bf16* __restrict__ C,
    int N, int K, int m0, int n0, int relu)
{
  __shared__ __align__(16) bf16 As[128 * 72];
  __shared__ __align__(16) bf16 Bs[128 * 72];

  const int tid    = threadIdx.x;
  const int lane   = tid & 63;
  const int wave   = tid >> 6;
  const int lane15 = lane & 15;
  const int quad   = lane >> 4;
  const int wm     = (wave & 1) << 6;
  const int wn     = (wave >> 1) << 6;

  f32x4 acc[4][4] = {};

  const bf16* Ab = A + (size_t)m0 * K;
  const bf16* Bb = B + (size_t)n0 * K;

  for (int k0 = 0; k0 < K; k0 += 64) {
    bf16x8 ar[4], br[4];
#pragma unroll
    for (int i = 0; i < 4; ++i) {
      const int c = i * 256 + tid;
      const int row = c >> 3, col = (c & 7) * 8;
      ar[i] = *(const bf16x8*)&Ab[(size_t)row * K + k0 + col];
      br[i] = *(const bf16x8*)&Bb[(size_t)row * K + k0 + col];
    }
    __syncthreads();   // previous iteration's fragment reads complete
#pragma unroll
    for (int i = 0; i < 4; ++i) {
      const int c = i * 256 + tid;
      const int row = c >> 3, col = c & 7;
      *(bf16x8*)&As[row * 72 + col * 8] = ar[i];
      *(bf16x8*)&Bs[row * 72 + col * 8] = br[i];
    }
    __syncthreads();   // staging visible

#pragma unroll
    for (int kk = 0; kk < 2; ++kk) {
      bf16x8 af[4], bfr[4];
#pragma unroll
      for (int f = 0; f < 4; ++f) {
        const int ra = wm + f * 16 + lane15;
        af[f]  = *(const bf16x8*)&As[ra * 72 + (kk * 4 + quad) * 8];
        const int rb = wn + f * 16 + lane15;
        bfr[f] = *(const bf16x8*)&Bs[rb * 72 + (kk * 4 + quad) * 8];
      }
#pragma unroll
      for (int fm = 0; fm < 4; ++fm)
#pragma unroll
        for (int fn = 0; fn < 4; ++fn)
          acc[fm][fn] = __builtin_amdgcn_mfma_f32_16x16x32_bf16(
              af[fm], bfr[fn], acc[fm][fn], 0, 0, 0);
    }
  }

  // epilogue: C/D layout col=lane&15, row=quad*4+reg  [m89-verified]
#pragma unroll
  for (int fm = 0; fm < 4; ++fm) {
#pragma unroll
    for (int fn = 0; fn < 4; ++fn) {
      const int col = n0 + wn + fn * 16 + lane15;
      const float bv = (float)bias[col];
#pragma unroll
      for (int r = 0; r < 4; ++r) {
        const int row = m0 + wm + fm * 16 + quad * 4 + r;
        float v = acc[fm][fn][r] + bv;
        if (relu) v = fmaxf(v, 0.0f);
        C[(size_t)row * N + col] = (bf16)v;
      }
    }
  }
}

__global__ __launch_bounds__(256, 2) void k_gemm(
    const bf16* __restrict__ A, const bf16* __restrict__ B,
    const bf16* __restrict__ bias, bf16* __restrict__ C,
    int N, int K, int relu)
{
  gemm_tile_128(A, B, bias, C, N, K, blockIdx.x * 128, blockIdx.y * 128, relu);
}

// Fused QKV: gridDim.z selects the projection (same A) -> 384 blocks in flight.
__global__ __launch_bounds__(256, 2) void k_gemm_qkv(
    const bf16* __restrict__ h,
    const bf16* __restrict__ Wq, const bf16* __restrict__ Wk, const bf16* __restrict__ Wv,
    const bf16* __restrict__ bq, const bf16* __restrict__ bk, const bf16* __restrict__ bv,
    bf16* __restrict__ q, bf16* __restrict__ k, bf16* __restrict__ v,
    int N, int K)
{
  const bf16* B; const bf16* bias; bf16* C;
  if (blockIdx.z == 0)      { B = Wq; bias = bq; C = q; }
  else if (blockIdx.z == 1) { B = Wk; bias = bk; C = k; }
  else                      { B = Wv; bias = bv; C = v; }
  gemm_tile_128(h, B, bias, C, N, K, blockIdx.x * 128, blockIdx.y * 128, 0);
}

// ---------------------------------------------------------------------------
// Pack adjacency (+self loops) into bitmask words: mb[row*64 + w] bit b =
// (adj[row][w*64+b] != 0) || (row == w*64+b).  One word per wave via __ballot.
// ---------------------------------------------------------------------------
__global__ __launch_bounds__(256) void k_packmask(
    const int* __restrict__ adj, unsigned long long* __restrict__ mb)
{
  const int gw   = (int)((blockIdx.x * 256 + threadIdx.x) >> 6); // word index
  const int lane = threadIdx.x & 63;
  const int a    = adj[(size_t)gw * 64 + lane];
  unsigned long long m = __ballot(a != 0);
  const int row = gw >> 6, wc = gw & 63;
  if ((row >> 6) == wc) m |= 1ull << (row & 63);
  if (lane == 0) mb[gw] = m;
}

// ---------------------------------------------------------------------------
// Transpose V: v[4096][512] -> vt[512][4096] so PV B-fragments are contiguous.
// ---------------------------------------------------------------------------
__global__ __launch_bounds__(256) void k_transpose_v(
    const bf16* __restrict__ v, bf16* __restrict__ vt)
{
  __shared__ __align__(16) bf16 T[64 * 72];
  const int r0 = blockIdx.x * 64;  // key tile
  const int c0 = blockIdx.y * 64;  // (head,dim) tile
  const int tid = threadIdx.x;
#pragma unroll
  for (int rr = 0; rr < 2; ++rr) {
    int idx = rr * 256 + tid;
    int kr = idx >> 3, ch = (idx & 7) * 8;
    *(bf16x8*)&T[kr * 72 + ch] = *(const bf16x8*)&v[(size_t)(r0 + kr) * 512 + c0 + ch];
  }
  __syncthreads();
#pragma unroll
  for (int rr = 0; rr < 2; ++rr) {
    int idx = rr * 256 + tid;
    int cr = idx >> 3, ch = idx & 7;
    bf16x8 y;
#pragma unroll
    for (int j = 0; j < 8; ++j) y[j] = T[(ch * 8 + j) * 72 + cr];
    *(bf16x8*)&vt[(size_t)(c0 + cr) * 4096 + r0 + ch * 8] = y;
  }
}

// ---------------------------------------------------------------------------
// Flash attention, one block = (head, 64-query tile), 4 waves x 16 query rows.
// ---------------------------------------------------------------------------
__global__ __launch_bounds__(256, 2) void k_attn(
    const bf16* __restrict__ Q, const bf16* __restrict__ Km,
    const bf16* __restrict__ Vt, const unsigned long long* __restrict__ mb,
    bf16* __restrict__ ctx)
{
  __shared__ __align__(16) bf16  Ks[64 * 72];      // [key][dim]
  __shared__ __align__(16) bf16  Vs[64 * 72];      // [dim][key]
  __shared__ __align__(16) float Pl[4][16 * 68];   // per-wave P round-trip

  const int tid    = threadIdx.x;
  const int wave   = tid >> 6;
  const int lane   = tid & 63;
  const int lane15 = lane & 15;
  const int quad   = lane >> 4;
  const int hd     = blockIdx.x & 7;
  const int qt     = blockIdx.x >> 3;
  const int qrow   = qt * 64 + wave * 16;

  bf16x8 qf[2];
#pragma unroll
  for (int c = 0; c < 2; ++c)
    qf[c] = *(const bf16x8*)&Q[(size_t)(qrow + lane15) * 512 + hd * 64 + c * 32 + quad * 8];

  float m_r[4], l_r[4];
  f32x4 o[4] = {};
#pragma unroll
  for (int r = 0; r < 4; ++r) { m_r[r] = -1e30f; l_r[r] = 0.0f; }

  for (int kt = 0; kt < 64; ++kt) {
    const int kb = kt * 64;
#pragma unroll
    for (int rr = 0; rr < 2; ++rr) {
      int idx = rr * 256 + tid;
      int a = idx >> 3, ch = (idx & 7) * 8;
      *(bf16x8*)&Ks[a * 72 + ch] = *(const bf16x8*)&Km[(size_t)(kb + a) * 512 + hd * 64 + ch];
      *(bf16x8*)&Vs[a * 72 + ch] = *(const bf16x8*)&Vt[(size_t)(hd * 64 + a) * 4096 + kb + ch];
    }
    __syncthreads();

    unsigned long long mw[4];
#pragma unroll
    for (int r = 0; r < 4; ++r)
      mw[r] = mb[(size_t)(qrow + quad * 4 + r) * 64 + kt] >> lane15;

    f32x4 sv[4];
#pragma unroll
    for (int g = 0; g < 4; ++g) {
      bf16x8 k0f = *(const bf16x8*)&Ks[(g * 16 + lane15) * 72 + quad * 8];
      bf16x8 k1f = *(const bf16x8*)&Ks[(g * 16 + lane15) * 72 + 32 + quad * 8];
      f32x4 s = {};
      s = __builtin_amdgcn_mfma_f32_16x16x32_bf16(qf[0], k0f, s, 0, 0, 0);
      s = __builtin_amdgcn_mfma_f32_16x16x32_bf16(qf[1], k1f, s, 0, 0, 0);
      sv[g] = s;
    }

#pragma unroll
    for (int r = 0; r < 4; ++r) {
      float tm = -1e30f;
#pragma unroll
      for (int g = 0; g < 4; ++g) {
        float val = sv[g][r] * 0.125f;
        sv[g][r] = val;
        bool ok = ((mw[r] >> (g * 16)) & 1ull) != 0;
        tm = fmaxf(tm, ok ? val : -1e30f);
      }
#pragma unroll
      for (int d = 1; d < 16; d <<= 1) tm = fmaxf(tm, __shfl_xor(tm, d, 64));
      const float mn = fmaxf(m_r[r], tm);
      const float al = __expf(m_r[r] - mn);
      m_r[r] = mn;
      l_r[r] *= al;
#pragma unroll
      for (int g2 = 0; g2 < 4; ++g2) o[g2][r] *= al;
      float ts = 0.0f;
#pragma unroll
      for (int g = 0; g < 4; ++g) {
        bool ok = ((mw[r] >> (g * 16)) & 1ull) != 0;
        float p = ok ? __expf(sv[g][r] - mn) : 0.0f;
        ts += p;
        Pl[wave][(quad * 4 + r) * 68 + g * 16 + lane15] = p;
      }
#pragma unroll
      for (int d = 1; d < 16; d <<= 1) ts += __shfl_xor(ts, d, 64);
      l_r[r] += ts;
    }

#pragma unroll
    for (int c2 = 0; c2 < 2; ++c2) {
      const float* pr = &Pl[wave][lane15 * 68 + c2 * 32 + quad * 8];
      f32x4 p0 = *(const f32x4*)pr;
      f32x4 p1 = *(const f32x4*)(pr + 4);
      bf16x8 pa;
#pragma unroll
      for (int j = 0; j < 4; ++j) { pa[j] = (bf16)p0[j]; pa[j + 4] = (bf16)p1[j]; }
#pragma unroll
      for (int g2 = 0; g2 < 4; ++g2) {
        bf16x8 vf = *(const bf16x8*)&Vs[(g2 * 16 + lane15) * 72 + c2 * 32 + quad * 8];
        o[g2] = __builtin_amdgcn_mfma_f32_16x16x32_bf16(pa, vf, o[g2], 0, 0, 0);
      }
    }
    __syncthreads();
  }

#pragma unroll
  for (int g2 = 0; g2 < 4; ++g2)
#pragma unroll
    for (int r = 0; r < 4; ++r) {
      const int row = qrow + quad * 4 + r;
      ctx[(size_t)row * 512 + hd * 64 + g2 * 16 + lane15] = (bf16)(o[g2][r] / l_r[r]);
    }
}

// ---------------------------------------------------------------------------
// Fused residual-add + LayerNorm. bf16 in; out bf16 (F32OUT=0) or fp32 (=1).
// ---------------------------------------------------------------------------
template <int F32OUT>
__global__ __launch_bounds__(256) void k_addln(
    const bf16* __restrict__ x, const bf16* __restrict__ y,
    const bf16* __restrict__ gam, const bf16* __restrict__ bet,
    void* __restrict__ out)
{
  const int wave = threadIdx.x >> 6, lane = threadIdx.x & 63;
  const int row  = blockIdx.x * 4 + wave;
  const size_t base = (size_t)row * 512 + lane * 8;
  bf16x8 xv = *(const bf16x8*)(x + base);
  bf16x8 yv = *(const bf16x8*)(y + base);
  float v[8], s = 0.0f, s2 = 0.0f;
#pragma unroll
  for (int j = 0; j < 8; ++j) {
    v[j] = (float)xv[j] + (float)yv[j];
    s += v[j]; s2 += v[j] * v[j];
  }
#pragma unroll
  for (int d = 1; d < 64; d <<= 1) { s += __shfl_xor(s, d, 64); s2 += __shfl_xor(s2, d, 64); }
  const float mu  = s * (1.0f / 512.0f);
  const float var = s2 * (1.0f / 512.0f) - mu * mu;
  const float rs  = rsqrtf(var + 1e-5f);
  bf16x8 gv = *(const bf16x8*)(gam + lane * 8);
  bf16x8 bv = *(const bf16x8*)(bet + lane * 8);
  if (F32OUT) {
    float* o = (float*)out + base;
#pragma unroll
    for (int j = 0; j < 8; ++j)
      o[j] = ((v[j] - mu) * rs) * (float)gv[j] + (float)bv[j];
  } else {
    bf16x8 ov;
#pragma unroll
    for (int j = 0; j < 8; ++j)
      ov[j] = (bf16)(((v[j] - mu) * rs) * (float)gv[j] + (float)bv[j]);
    *(bf16x8*)((bf16*)out + base) = ov;
  }
}

// ---------------------------------------------------------------------------
extern "C" void kernel_launch(void* const* d_in, const int* in_sizes, int n_in,
                              void* d_out, int out_size, void* d_ws, size_t ws_size,
                              hipStream_t stream)
{
  // Inputs are fp32 (per the reference); adj is int32.
  const int* adj = (const int*)d_in[1];

  char* ws = (char*)d_ws;
  const size_t MB = 1024 * 1024;

  // --- bf16 arena (fp32 inputs cast once per call) ---------------------------
  // h:4MB @0 | Wq/Wk/Wv/Wo: 0.5MB each @4,4.5,5,5.5 | W1:2MB @6 | W2:2MB @8
  // small vecs: 16KB slots from @10MB
  bf16* hb  = (bf16*)(ws + 0 * MB);
  bf16* Wqb = (bf16*)(ws + 4 * MB);
  bf16* Wkb = (bf16*)(ws + 4 * MB + 512 * 1024);
  bf16* Wvb = (bf16*)(ws + 5 * MB);
  bf16* Wob = (bf16*)(ws + 5 * MB + 512 * 1024);
  bf16* W1b = (bf16*)(ws + 6 * MB);
  bf16* W2b = (bf16*)(ws + 8 * MB);
  char* vecbase = ws + 10 * MB;
  bf16* bqb  = (bf16*)(vecbase + 0 * 16384);
  bf16* bkb  = (bf16*)(vecbase + 1 * 16384);
  bf16* bvb  = (bf16*)(vecbase + 2 * 16384);
  bf16* bob  = (bf16*)(vecbase + 3 * 16384);
  bf16* b1b  = (bf16*)(vecbase + 4 * 16384);
  bf16* b2b  = (bf16*)(vecbase + 5 * 16384);
  bf16* g1b  = (bf16*)(vecbase + 6 * 16384);
  bf16* be1b = (bf16*)(vecbase + 7 * 16384);
  bf16* g2b  = (bf16*)(vecbase + 8 * 16384);
  bf16* be2b = (bf16*)(vecbase + 9 * 16384);

  // --- intermediates ---------------------------------------------------------
  bf16* q    = (bf16*)(ws + 12 * MB);   // 4 MB
  bf16* k    = (bf16*)(ws + 16 * MB);   // 4 MB
  bf16* v    = (bf16*)(ws + 20 * MB);   // 4 MB
  bf16* vt   = (bf16*)(ws + 24 * MB);   // 4 MB
  unsigned long long* mbits = (unsigned long long*)(ws + 28 * MB); // 2 MB
  bf16* ctx  = (bf16*)(ws + 30 * MB);   // 4 MB
  bf16* att  = (bf16*)(ws + 12 * MB);   // over q (dead after attention)
  bf16* h1   = (bf16*)(ws + 16 * MB);   // over k (dead)
  bf16* ff1  = (bf16*)(ws + 20 * MB);   // 16 MB over v/vt/mbits/ctx (dead)
  bf16* ff2  = (bf16*)(ws + 12 * MB);   // over att (dead after LN1)
  // peak ws use: 36 MB

  // --- batched cast ----------------------------------------------------------
  CastArgs ca;
  const int srcIdx[17] = {0, 2, 3, 4, 5, 6, 7, 8, 9, 10, 11, 12, 13, 14, 15, 16, 17};
  bf16* dsts[17] = {hb, Wqb, bqb, Wkb, bkb, Wvb, bvb, Wob, bob,
                    W1b, b1b, W2b, b2b, g1b, be1b, g2b, be2b};
  int cum = 0;
  for (int t = 0; t < 17; ++t) {
    ca.src[t] = (const float*)d_in[srcIdx[t]];
    ca.dst[t] = dsts[t];
    ca.cum[t] = cum;
    cum += in_sizes[srcIdx[t]] / 8;
  }
  ca.cum[17] = cum;

  const dim3 blk(256);
  k_cast<<<dim3((cum + 255) / 256), blk, 0, stream>>>(ca, cum);

  // 1. QKV projections (fused, 384 blocks)
  k_gemm_qkv<<<dim3(32, 4, 3), blk, 0, stream>>>(hb, Wqb, Wkb, Wvb, bqb, bkb, bvb,
                                                 q, k, v, 512, 512);
  // 2. transpose V for PV fragment loads
  k_transpose_v<<<dim3(64, 8), blk, 0, stream>>>(v, vt);
  // 3. pack adjacency(+I) into bitmask (64 MB -> 2 MB)
  k_packmask<<<dim3(65536), blk, 0, stream>>>(adj, mbits);
  // 4. flash attention -> ctx
  k_attn<<<dim3(512), blk, 0, stream>>>(q, k, vt, mbits, ctx);
  // 5. output projection
  k_gemm<<<dim3(32, 4), blk, 0, stream>>>(ctx, Wob, bob, att, 512, 512, 0);
  // 6. h1 = LN(h + att)  (bf16 out)
  k_addln<0><<<dim3(1024), blk, 0, stream>>>(hb, att, g1b, be1b, (void*)h1);
  // 7. ff1 = relu(h1 @ W1^T + b1)   [4096 x 2048]
  k_gemm<<<dim3(32, 16), blk, 0, stream>>>(h1, W1b, b1b, ff1, 2048, 512, 1);
  // 8. ff2 = ff1 @ W2^T + b2        [4096 x 512, K=2048]
  k_gemm<<<dim3(32, 4), blk, 0, stream>>>(ff1, W2b, b2b, ff2, 512, 2048, 0);
  // 9. out = LN(h1 + ff2)  (fp32 out)
  k_addln<1><<<dim3(1024), blk, 0, stream>>>(h1, ff2, g2b, be2b, d_out);
}

// Round 4
// 322.255 us; speedup vs baseline: 1.2150x; 1.2150x over previous
//
#include <hip/hip_runtime.h>
#include <stdint.h>
#include <stddef.h>

typedef __bf16 bf16;
typedef __bf16 bf16x8 __attribute__((ext_vector_type(8)));
typedef float  f32x4  __attribute__((ext_vector_type(4)));

// ---------------------------------------------------------------------------
// Batched fp32 -> bf16 cast.
// ---------------------------------------------------------------------------
struct CastArgs {
  const float* src[17];
  bf16*        dst[17];
  int          cum[18];   // cumulative vec8 counts
};

__global__ __launch_bounds__(256) void k_cast(CastArgs a, int total8)
{
  const int g = blockIdx.x * 256 + threadIdx.x;
  if (g >= total8) return;
  int t = 0;
  while (a.cum[t + 1] <= g) ++t;
  const int i = g - a.cum[t];
  const float4* s = (const float4*)(a.src[t]) + (size_t)i * 2;
  const float4 x0 = s[0], x1 = s[1];
  bf16x8 y;
  y[0] = (bf16)x0.x; y[1] = (bf16)x0.y; y[2] = (bf16)x0.z; y[3] = (bf16)x0.w;
  y[4] = (bf16)x1.x; y[5] = (bf16)x1.y; y[6] = (bf16)x1.z; y[7] = (bf16)x1.w;
  *(bf16x8*)(a.dst[t] + (size_t)i * 8) = y;
}

// ---------------------------------------------------------------------------
// GEMM: C[M,N] = A[M,K] @ B[N,K]^T + bias, optional ReLU. 128x128 tile.
// ---------------------------------------------------------------------------
__device__ __forceinline__ void gemm_tile_128(
    const bf16* __restrict__ A, const bf16* __restrict__ B,
    const bf16* __restrict__ bias, bf16* __restrict__ C,
    int N, int K, int m0, int n0, int relu)
{
  __shared__ __align__(16) bf16 As[128 * 72];
  __shared__ __align__(16) bf16 Bs[128 * 72];

  const int tid    = threadIdx.x;
  const int lane   = tid & 63;
  const int wave   = tid >> 6;
  const int lane15 = lane & 15;
  const int quad   = lane >> 4;
  const int wm     = (wave & 1) << 6;
  const int wn     = (wave >> 1) << 6;

  f32x4 acc[4][4] = {};

  const bf16* Ab = A + (size_t)m0 * K;
  const bf16* Bb = B + (size_t)n0 * K;

  for (int k0 = 0; k0 < K; k0 += 64) {
    bf16x8 ar[4], br[4];
#pragma unroll
    for (int i = 0; i < 4; ++i) {
      const int c = i * 256 + tid;
      const int row = c >> 3, col = (c & 7) * 8;
      ar[i] = *(const bf16x8*)&Ab[(size_t)row * K + k0 + col];
      br[i] = *(const bf16x8*)&Bb[(size_t)row * K + k0 + col];
    }
    __syncthreads();
#pragma unroll
    for (int i = 0; i < 4; ++i) {
      const int c = i * 256 + tid;
      const int row = c >> 3, col = c & 7;
      *(bf16x8*)&As[row * 72 + col * 8] = ar[i];
      *(bf16x8*)&Bs[row * 72 + col * 8] = br[i];
    }
    __syncthreads();

#pragma unroll
    for (int kk = 0; kk < 2; ++kk) {
      bf16x8 af[4], bfr[4];
#pragma unroll
      for (int f = 0; f < 4; ++f) {
        const int ra = wm + f * 16 + lane15;
        af[f]  = *(const bf16x8*)&As[ra * 72 + (kk * 4 + quad) * 8];
        const int rb = wn + f * 16 + lane15;
        bfr[f] = *(const bf16x8*)&Bs[rb * 72 + (kk * 4 + quad) * 8];
      }
#pragma unroll
      for (int fm = 0; fm < 4; ++fm)
#pragma unroll
        for (int fn = 0; fn < 4; ++fn)
          acc[fm][fn] = __builtin_amdgcn_mfma_f32_16x16x32_bf16(
              af[fm], bfr[fn], acc[fm][fn], 0, 0, 0);
    }
  }

#pragma unroll
  for (int fm = 0; fm < 4; ++fm) {
#pragma unroll
    for (int fn = 0; fn < 4; ++fn) {
      const int col = n0 + wn + fn * 16 + lane15;
      const float bv = (float)bias[col];
#pragma unroll
      for (int r = 0; r < 4; ++r) {
        const int row = m0 + wm + fm * 16 + quad * 4 + r;
        float v = acc[fm][fn][r] + bv;
        if (relu) v = fmaxf(v, 0.0f);
        C[(size_t)row * N + col] = (bf16)v;
      }
    }
  }
}

__global__ __launch_bounds__(256, 2) void k_gemm(
    const bf16* __restrict__ A, const bf16* __restrict__ B,
    const bf16* __restrict__ bias, bf16* __restrict__ C,
    int N, int K, int relu)
{
  gemm_tile_128(A, B, bias, C, N, K, blockIdx.x * 128, blockIdx.y * 128, relu);
}

__global__ __launch_bounds__(256, 2) void k_gemm_qkv(
    const bf16* __restrict__ h,
    const bf16* __restrict__ Wq, const bf16* __restrict__ Wk, const bf16* __restrict__ Wv,
    const bf16* __restrict__ bq, const bf16* __restrict__ bk, const bf16* __restrict__ bv,
    bf16* __restrict__ q, bf16* __restrict__ k, bf16* __restrict__ v,
    int N, int K)
{
  const bf16* B; const bf16* bias; bf16* C;
  if (blockIdx.z == 0)      { B = Wq; bias = bq; C = q; }
  else if (blockIdx.z == 1) { B = Wk; bias = bk; C = k; }
  else                      { B = Wv; bias = bv; C = v; }
  gemm_tile_128(h, B, bias, C, N, K, blockIdx.x * 128, blockIdx.y * 128, 0);
}

// ---------------------------------------------------------------------------
// Split-K GEMM: writes f32 partials Cp[z][M][N], k-range [z*Ksplit, (z+1)*Ksplit).
// ---------------------------------------------------------------------------
__global__ __launch_bounds__(256, 2) void k_gemm_sk(
    const bf16* __restrict__ A, const bf16* __restrict__ B,
    float* __restrict__ Cp, int N, int K, int Ksplit)
{
  __shared__ __align__(16) bf16 As[128 * 72];
  __shared__ __align__(16) bf16 Bs[128 * 72];

  const int tid    = threadIdx.x;
  const int lane   = tid & 63;
  const int wave   = tid >> 6;
  const int lane15 = lane & 15;
  const int quad   = lane >> 4;
  const int wm     = (wave & 1) << 6;
  const int wn     = (wave >> 1) << 6;
  const int m0     = blockIdx.x * 128;
  const int n0     = blockIdx.y * 128;
  const int kbeg   = blockIdx.z * Ksplit;

  f32x4 acc[4][4] = {};

  const bf16* Ab = A + (size_t)m0 * K;
  const bf16* Bb = B + (size_t)n0 * K;

  for (int k0 = kbeg; k0 < kbeg + Ksplit; k0 += 64) {
    bf16x8 ar[4], br[4];
#pragma unroll
    for (int i = 0; i < 4; ++i) {
      const int c = i * 256 + tid;
      const int row = c >> 3, col = (c & 7) * 8;
      ar[i] = *(const bf16x8*)&Ab[(size_t)row * K + k0 + col];
      br[i] = *(const bf16x8*)&Bb[(size_t)row * K + k0 + col];
    }
    __syncthreads();
#pragma unroll
    for (int i = 0; i < 4; ++i) {
      const int c = i * 256 + tid;
      const int row = c >> 3, col = c & 7;
      *(bf16x8*)&As[row * 72 + col * 8] = ar[i];
      *(bf16x8*)&Bs[row * 72 + col * 8] = br[i];
    }
    __syncthreads();

#pragma unroll
    for (int kk = 0; kk < 2; ++kk) {
      bf16x8 af[4], bfr[4];
#pragma unroll
      for (int f = 0; f < 4; ++f) {
        const int ra = wm + f * 16 + lane15;
        af[f]  = *(const bf16x8*)&As[ra * 72 + (kk * 4 + quad) * 8];
        const int rb = wn + f * 16 + lane15;
        bfr[f] = *(const bf16x8*)&Bs[rb * 72 + (kk * 4 + quad) * 8];
      }
#pragma unroll
      for (int fm = 0; fm < 4; ++fm)
#pragma unroll
        for (int fn = 0; fn < 4; ++fn)
          acc[fm][fn] = __builtin_amdgcn_mfma_f32_16x16x32_bf16(
              af[fm], bfr[fn], acc[fm][fn], 0, 0, 0);
    }
  }

  float* Cz = Cp + (size_t)blockIdx.z * 4096 * N;
#pragma unroll
  for (int fm = 0; fm < 4; ++fm)
#pragma unroll
    for (int fn = 0; fn < 4; ++fn) {
      const int col = n0 + wn + fn * 16 + lane15;
#pragma unroll
      for (int r = 0; r < 4; ++r) {
        const int row = m0 + wm + fm * 16 + quad * 4 + r;
        Cz[(size_t)row * N + col] = acc[fm][fn][r];
      }
    }
}

// Combine 2 split-K partials + bias -> bf16.
__global__ __launch_bounds__(256) void k_sk_combine(
    const float* __restrict__ Cp, const bf16* __restrict__ bias,
    bf16* __restrict__ C, int N)
{
  const int g = blockIdx.x * 256 + threadIdx.x;
  const size_t base = (size_t)g * 8;
  const int col = (int)(base % (size_t)N);
  const float* p0 = Cp + base;
  const float* p1 = Cp + (size_t)4096 * N + base;
  f32x4 a0 = *(const f32x4*)p0, a1 = *(const f32x4*)(p0 + 4);
  f32x4 b0 = *(const f32x4*)p1, b1 = *(const f32x4*)(p1 + 4);
  bf16x8 y;
#pragma unroll
  for (int j = 0; j < 4; ++j) {
    y[j]     = (bf16)(a0[j] + b0[j] + (float)bias[col + j]);
    y[4 + j] = (bf16)(a1[j] + b1[j] + (float)bias[col + 4 + j]);
  }
  *(bf16x8*)(C + base) = y;
}

// ---------------------------------------------------------------------------
// Pack adjacency (+self loops) into 64-bit mask words.
// ---------------------------------------------------------------------------
__global__ __launch_bounds__(256) void k_packmask(
    const int* __restrict__ adj, unsigned long long* __restrict__ mb)
{
  const int gw   = (int)((blockIdx.x * 256 + threadIdx.x) >> 6);
  const int lane = threadIdx.x & 63;
  const int a    = adj[(size_t)gw * 64 + lane];
  unsigned long long m = __ballot(a != 0);
  const int row = gw >> 6, wc = gw & 63;
  if ((row >> 6) == wc) m |= 1ull << (row & 63);
  if (lane == 0) mb[gw] = m;
}

// ---------------------------------------------------------------------------
// Transpose V: v[4096][512] -> vt[512][4096].
// ---------------------------------------------------------------------------
__global__ __launch_bounds__(256) void k_transpose_v(
    const bf16* __restrict__ v, bf16* __restrict__ vt)
{
  __shared__ __align__(16) bf16 T[64 * 72];
  const int r0 = blockIdx.x * 64;
  const int c0 = blockIdx.y * 64;
  const int tid = threadIdx.x;
#pragma unroll
  for (int rr = 0; rr < 2; ++rr) {
    int idx = rr * 256 + tid;
    int kr = idx >> 3, ch = (idx & 7) * 8;
    *(bf16x8*)&T[kr * 72 + ch] = *(const bf16x8*)&v[(size_t)(r0 + kr) * 512 + c0 + ch];
  }
  __syncthreads();
#pragma unroll
  for (int rr = 0; rr < 2; ++rr) {
    int idx = rr * 256 + tid;
    int cr = idx >> 3, ch = idx & 7;
    bf16x8 y;
#pragma unroll
    for (int j = 0; j < 8; ++j) y[j] = T[(ch * 8 + j) * 72 + cr];
    *(bf16x8*)&vt[(size_t)(c0 + cr) * 4096 + r0 + ch * 8] = y;
  }
}

// ---------------------------------------------------------------------------
// Flash attention, split-K x4. Block = (qt, head, split); 4 waves x 16 q-rows.
// NO online max: scores are bounded (|s| << 88), so p = exp(s) directly and
// partials are purely additive across splits. Denominator l accumulated via
// ones-vector MFMA (same C-layout rows as O). P transits LDS as bf16
// (C-layout -> A-layout). Unnormalized O (bf16) + l (f32) written per split.
// ---------------------------------------------------------------------------
__global__ __launch_bounds__(256, 4) void k_attn(
    const bf16* __restrict__ Q, const bf16* __restrict__ Km,
    const bf16* __restrict__ Vt, const unsigned long long* __restrict__ mb,
    bf16* __restrict__ Opart, float* __restrict__ Lpart)
{
  __shared__ __align__(16) bf16 Ks[64 * 72];      // [key][dim]
  __shared__ __align__(16) bf16 Vs[64 * 72];      // [dim][key]
  __shared__ __align__(16) bf16 Plb[4][16 * 72];  // per-wave P (bf16)

  const int tid    = threadIdx.x;
  const int wave   = tid >> 6;
  const int lane   = tid & 63;
  const int lane15 = lane & 15;
  const int quad   = lane >> 4;
  const int sp     = blockIdx.x & 3;
  const int hd     = (blockIdx.x >> 2) & 7;
  const int qt     = blockIdx.x >> 5;
  const int qrow   = qt * 64 + wave * 16;

  bf16x8 qf[2];
#pragma unroll
  for (int c = 0; c < 2; ++c)
    qf[c] = *(const bf16x8*)&Q[(size_t)(qrow + lane15) * 512 + hd * 64 + c * 32 + quad * 8];

  bf16x8 ones;
#pragma unroll
  for (int j = 0; j < 8; ++j) ones[j] = (bf16)1.0f;

  f32x4 o[4] = {};
  f32x4 la   = {};

  for (int kt = sp * 16; kt < sp * 16 + 16; ++kt) {
    const int kb = kt * 64;
#pragma unroll
    for (int rr = 0; rr < 2; ++rr) {
      int idx = rr * 256 + tid;
      int a = idx >> 3, ch = (idx & 7) * 8;
      *(bf16x8*)&Ks[a * 72 + ch] = *(const bf16x8*)&Km[(size_t)(kb + a) * 512 + hd * 64 + ch];
      *(bf16x8*)&Vs[a * 72 + ch] = *(const bf16x8*)&Vt[(size_t)(hd * 64 + a) * 4096 + kb + ch];
    }
    __syncthreads();

    unsigned long long mw[4];
#pragma unroll
    for (int r = 0; r < 4; ++r)
      mw[r] = mb[(size_t)(qrow + quad * 4 + r) * 64 + kt] >> lane15;

    // S = Q K^T for 16 q-rows x 64 keys; p = mask ? exp(s/8) : 0 -> LDS (bf16)
#pragma unroll
    for (int g = 0; g < 4; ++g) {
      bf16x8 k0f = *(const bf16x8*)&Ks[(g * 16 + lane15) * 72 + quad * 8];
      bf16x8 k1f = *(const bf16x8*)&Ks[(g * 16 + lane15) * 72 + 32 + quad * 8];
      f32x4 s = {};
      s = __builtin_amdgcn_mfma_f32_16x16x32_bf16(qf[0], k0f, s, 0, 0, 0);
      s = __builtin_amdgcn_mfma_f32_16x16x32_bf16(qf[1], k1f, s, 0, 0, 0);
#pragma unroll
      for (int r = 0; r < 4; ++r) {
        const bool ok = ((mw[r] >> (g * 16)) & 1ull) != 0;
        const float p = ok ? __expf(s[r] * 0.125f) : 0.0f;
        Plb[wave][(quad * 4 + r) * 72 + g * 16 + lane15] = (bf16)p;
      }
    }

    // O += P V ; l += P 1  (wave-private LDS round-trip, no barrier needed)
#pragma unroll
    for (int c2 = 0; c2 < 2; ++c2) {
      bf16x8 pa = *(const bf16x8*)&Plb[wave][lane15 * 72 + c2 * 32 + quad * 8];
      la = __builtin_amdgcn_mfma_f32_16x16x32_bf16(pa, ones, la, 0, 0, 0);
#pragma unroll
      for (int g2 = 0; g2 < 4; ++g2) {
        bf16x8 vf = *(const bf16x8*)&Vs[(g2 * 16 + lane15) * 72 + c2 * 32 + quad * 8];
        o[g2] = __builtin_amdgcn_mfma_f32_16x16x32_bf16(pa, vf, o[g2], 0, 0, 0);
      }
    }
    __syncthreads();
  }

  bf16* Oz = Opart + (size_t)sp * 4096 * 512;
#pragma unroll
  for (int g2 = 0; g2 < 4; ++g2)
#pragma unroll
    for (int r = 0; r < 4; ++r) {
      const int row = qrow + quad * 4 + r;
      Oz[(size_t)row * 512 + hd * 64 + g2 * 16 + lane15] = (bf16)o[g2][r];
    }
  if (lane15 == 0) {
#pragma unroll
    for (int r = 0; r < 4; ++r)
      Lpart[sp * 32768 + (qrow + quad * 4 + r) * 8 + hd] = la[r];
  }
}

// Combine attention partials: ctx = (sum_s O_s) / (sum_s l_s).
__global__ __launch_bounds__(256) void k_attn_combine(
    const bf16* __restrict__ Opart, const float* __restrict__ Lpart,
    bf16* __restrict__ ctx)
{
  const int g = blockIdx.x * 256 + threadIdx.x;   // 262144 threads
  const size_t base = (size_t)g * 8;
  const int row = g >> 6;
  const int hd  = (g & 63) >> 3;
  float acc[8] = {};
  float l = 0.0f;
#pragma unroll
  for (int s = 0; s < 4; ++s) {
    bf16x8 ov = *(const bf16x8*)&Opart[(size_t)s * 4096 * 512 + base];
#pragma unroll
    for (int j = 0; j < 8; ++j) acc[j] += (float)ov[j];
    l += Lpart[s * 32768 + row * 8 + hd];
  }
  const float rl = 1.0f / l;
  bf16x8 y;
#pragma unroll
  for (int j = 0; j < 8; ++j) y[j] = (bf16)(acc[j] * rl);
  *(bf16x8*)(ctx + base) = y;
}

// ---------------------------------------------------------------------------
// Fused residual-add + LayerNorm.
// ---------------------------------------------------------------------------
template <int F32OUT>
__global__ __launch_bounds__(256) void k_addln(
    const bf16* __restrict__ x, const bf16* __restrict__ y,
    const bf16* __restrict__ gam, const bf16* __restrict__ bet,
    void* __restrict__ out)
{
  const int wave = threadIdx.x >> 6, lane = threadIdx.x & 63;
  const int row  = blockIdx.x * 4 + wave;
  const size_t base = (size_t)row * 512 + lane * 8;
  bf16x8 xv = *(const bf16x8*)(x + base);
  bf16x8 yv = *(const bf16x8*)(y + base);
  float v[8], s = 0.0f, s2 = 0.0f;
#pragma unroll
  for (int j = 0; j < 8; ++j) {
    v[j] = (float)xv[j] + (float)yv[j];
    s += v[j]; s2 += v[j] * v[j];
  }
#pragma unroll
  for (int d = 1; d < 64; d <<= 1) { s += __shfl_xor(s, d, 64); s2 += __shfl_xor(s2, d, 64); }
  const float mu  = s * (1.0f / 512.0f);
  const float var = s2 * (1.0f / 512.0f) - mu * mu;
  const float rs  = rsqrtf(var + 1e-5f);
  bf16x8 gv = *(const bf16x8*)(gam + lane * 8);
  bf16x8 bv = *(const bf16x8*)(bet + lane * 8);
  if (F32OUT) {
    float* o = (float*)out + base;
#pragma unroll
    for (int j = 0; j < 8; ++j)
      o[j] = ((v[j] - mu) * rs) * (float)gv[j] + (float)bv[j];
  } else {
    bf16x8 ov;
#pragma unroll
    for (int j = 0; j < 8; ++j)
      ov[j] = (bf16)(((v[j] - mu) * rs) * (float)gv[j] + (float)bv[j]);
    *(bf16x8*)((bf16*)out + base) = ov;
  }
}

// ---------------------------------------------------------------------------
extern "C" void kernel_launch(void* const* d_in, const int* in_sizes, int n_in,
                              void* d_out, int out_size, void* d_ws, size_t ws_size,
                              hipStream_t stream)
{
  const int* adj = (const int*)d_in[1];

  char* ws = (char*)d_ws;
  const size_t MB = 1024 * 1024;

  // --- bf16 arena ------------------------------------------------------------
  bf16* hb  = (bf16*)(ws + 0 * MB);
  bf16* Wqb = (bf16*)(ws + 4 * MB);
  bf16* Wkb = (bf16*)(ws + 4 * MB + 512 * 1024);
  bf16* Wvb = (bf16*)(ws + 5 * MB);
  bf16* Wob = (bf16*)(ws + 5 * MB + 512 * 1024);
  bf16* W1b = (bf16*)(ws + 6 * MB);
  bf16* W2b = (bf16*)(ws + 8 * MB);
  char* vecbase = ws + 10 * MB;
  bf16* bqb  = (bf16*)(vecbase + 0 * 16384);
  bf16* bkb  = (bf16*)(vecbase + 1 * 16384);
  bf16* bvb  = (bf16*)(vecbase + 2 * 16384);
  bf16* bob  = (bf16*)(vecbase + 3 * 16384);
  bf16* b1b  = (bf16*)(vecbase + 4 * 16384);
  bf16* b2b  = (bf16*)(vecbase + 5 * 16384);
  bf16* g1b  = (bf16*)(vecbase + 6 * 16384);
  bf16* be1b = (bf16*)(vecbase + 7 * 16384);
  bf16* g2b  = (bf16*)(vecbase + 8 * 16384);
  bf16* be2b = (bf16*)(vecbase + 9 * 16384);

  // --- intermediates (lifetime-packed) --------------------------------------
  bf16* q    = (bf16*)(ws + 12 * MB);   // dead after attn
  bf16* k    = (bf16*)(ws + 16 * MB);   // dead after attn
  bf16* v    = (bf16*)(ws + 20 * MB);   // dead after transpose
  bf16* vt   = (bf16*)(ws + 24 * MB);   // dead after attn
  unsigned long long* mbits = (unsigned long long*)(ws + 28 * MB); // 2 MB
  bf16* ctx  = (bf16*)(ws + 30 * MB);   // dead after Wo gemm
  bf16*  Opart = (bf16*)(ws + 34 * MB); // 16 MB, dead after attn combine
  float* Lpart = (float*)(ws + 50 * MB);// 0.5 MB
  float* skP  = (float*)(ws + 34 * MB); // 16 MB f32 partials (reuse Opart region)
  bf16* att  = (bf16*)(ws + 12 * MB);   // over q
  bf16* h1   = (bf16*)(ws + 30 * MB);   // over ctx
  bf16* ff1  = (bf16*)(ws + 12 * MB);   // 16 MB over q/att,k,v,vt (all dead)
  bf16* ff2  = (bf16*)(ws + 12 * MB);   // over ff1 (combine runs after sk gemm)
  // peak ws use: 50.5 MB

  // --- batched cast ----------------------------------------------------------
  CastArgs ca;
  const int srcIdx[17] = {0, 2, 3, 4, 5, 6, 7, 8, 9, 10, 11, 12, 13, 14, 15, 16, 17};
  bf16* dsts[17] = {hb, Wqb, bqb, Wkb, bkb, Wvb, bvb, Wob, bob,
                    W1b, b1b, W2b, b2b, g1b, be1b, g2b, be2b};
  int cum = 0;
  for (int t = 0; t < 17; ++t) {
    ca.src[t] = (const float*)d_in[srcIdx[t]];
    ca.dst[t] = dsts[t];
    ca.cum[t] = cum;
    cum += in_sizes[srcIdx[t]] / 8;
  }
  ca.cum[17] = cum;

  const dim3 blk(256);
  k_cast<<<dim3((cum + 255) / 256), blk, 0, stream>>>(ca, cum);

  // 1. QKV projections
  k_gemm_qkv<<<dim3(32, 4, 3), blk, 0, stream>>>(hb, Wqb, Wkb, Wvb, bqb, bkb, bvb,
                                                 q, k, v, 512, 512);
  // 2. transpose V
  k_transpose_v<<<dim3(64, 8), blk, 0, stream>>>(v, vt);
  // 3. pack adjacency(+I)
  k_packmask<<<dim3(65536), blk, 0, stream>>>(adj, mbits);
  // 4. flash attention, split-K x4 (2048 blocks) + combine
  k_attn<<<dim3(2048), blk, 0, stream>>>(q, k, vt, mbits, Opart, Lpart);
  k_attn_combine<<<dim3(1024), blk, 0, stream>>>(Opart, Lpart, ctx);
  // 5. output projection, split-K x2 (256 blocks) + combine
  k_gemm_sk<<<dim3(32, 4, 2), blk, 0, stream>>>(ctx, Wob, skP, 512, 512, 256);
  k_sk_combine<<<dim3(1024), blk, 0, stream>>>(skP, bob, att, 512);
  // 6. h1 = LN(h + att)
  k_addln<0><<<dim3(1024), blk, 0, stream>>>(hb, att, g1b, be1b, (void*)h1);
  // 7. ff1 = relu(h1 @ W1^T + b1)
  k_gemm<<<dim3(32, 16), blk, 0, stream>>>(h1, W1b, b1b, ff1, 2048, 512, 1);
  // 8. ff2 = ff1 @ W2^T + b2, split-K x2 (256 blocks) + combine
  k_gemm_sk<<<dim3(32, 4, 2), blk, 0, stream>>>(ff1, W2b, skP, 512, 2048, 1024);
  k_sk_combine<<<dim3(1024), blk, 0, stream>>>(skP, b2b, ff2, 512);
  // 9. out = LN(h1 + ff2)
  k_addln<1><<<dim3(1024), blk, 0, stream>>>(h1, ff2, g2b, be2b, d_out);
}

// Round 5
// 311.783 us; speedup vs baseline: 1.2558x; 1.0336x over previous
//
#include <hip/hip_runtime.h>
#include <stdint.h>
#include <stddef.h>

typedef __bf16 bf16;
typedef __bf16 bf16x8 __attribute__((ext_vector_type(8)));
typedef float  f32x4  __attribute__((ext_vector_type(4)));

typedef __attribute__((address_space(3))) void       lds_void;
typedef __attribute__((address_space(1))) const void gbl_cvoid;

#define ASYNC_CP16(g, l) \
  __builtin_amdgcn_global_load_lds((gbl_cvoid*)(g), (lds_void*)(l), 16, 0, 0)

// chunk swizzle: spreads b128 fragment reads across all 32 banks (2-way floor)
__device__ __forceinline__ int swz(int r) { return (r & 7) ^ ((r & 8) >> 1); }

// ---------------------------------------------------------------------------
// Batched fp32 -> bf16 cast (h + 6 weight matrices only; vectors read raw).
// ---------------------------------------------------------------------------
struct CastArgs {
  const float* src[7];
  bf16*        dst[7];
  int          cum[8];   // cumulative vec8 counts
};

__global__ __launch_bounds__(256) void k_cast(CastArgs a, int total8)
{
  const int g = blockIdx.x * 256 + threadIdx.x;
  if (g >= total8) return;
  int t = 0;
  while (a.cum[t + 1] <= g) ++t;
  const int i = g - a.cum[t];
  const float4* s = (const float4*)(a.src[t]) + (size_t)i * 2;
  const float4 x0 = s[0], x1 = s[1];
  bf16x8 y;
  y[0] = (bf16)x0.x; y[1] = (bf16)x0.y; y[2] = (bf16)x0.z; y[3] = (bf16)x0.w;
  y[4] = (bf16)x1.x; y[5] = (bf16)x1.y; y[6] = (bf16)x1.z; y[7] = (bf16)x1.w;
  *(bf16x8*)(a.dst[t] + (size_t)i * 8) = y;
}

// ---------------------------------------------------------------------------
// Async-staged GEMM core (m97 structure): C = A[M,K] @ B[N,K]^T, 128x128 tile,
// BK=64, global_load_lds width=16, XOR-swizzled chunk placement.
// Accumulators returned in-place; epilogue differs per caller.
// ---------------------------------------------------------------------------
__device__ __forceinline__ void gemm_core_async(
    const bf16* __restrict__ A, const bf16* __restrict__ B,
    bf16* As, bf16* Bs, f32x4 (&acc)[4][4],
    int K, int m0, int n0, int kbeg, int kend)
{
  const int tid    = threadIdx.x;
  const int lane   = tid & 63;
  const int wave   = tid >> 6;
  const int lane15 = lane & 15;
  const int quad   = lane >> 4;
  const int wm     = (wave & 1) << 6;
  const int wn     = (wave >> 1) << 6;

  // staging map: wave-instr i covers chunks c=(wave*4+i)*64+lane.
  // LDS dest is implicit base+lane*16 => slot (row=c>>3, cpos=c&7) holds
  // global chunk (c&7) ^ swz(row).
  int srow[4], soff[4];
#pragma unroll
  for (int i = 0; i < 4; ++i) {
    int c   = ((wave * 4 + i) << 6) + lane;
    srow[i] = c >> 3;
    soff[i] = ((c & 7) ^ swz(srow[i])) * 8;
  }

  const bf16* Ab = A + (size_t)m0 * K;
  const bf16* Bb = B + (size_t)n0 * K;

  for (int k0 = kbeg; k0 < kend; k0 += 64) {
#pragma unroll
    for (int i = 0; i < 4; ++i) {
      ASYNC_CP16(Ab + (size_t)srow[i] * K + k0 + soff[i], &As[(wave * 4 + i) * 512]);
      ASYNC_CP16(Bb + (size_t)srow[i] * K + k0 + soff[i], &Bs[(wave * 4 + i) * 512]);
    }
    __syncthreads();   // drains vmcnt: async LDS writes visible

#pragma unroll
    for (int kk = 0; kk < 2; ++kk) {
      bf16x8 af[4], bfr[4];
#pragma unroll
      for (int f = 0; f < 4; ++f) {
        const int ra = wm + f * 16 + lane15;
        af[f]  = *(const bf16x8*)&As[ra * 64 + (((kk * 4 + quad) ^ swz(ra)) * 8)];
        const int rb = wn + f * 16 + lane15;
        bfr[f] = *(const bf16x8*)&Bs[rb * 64 + (((kk * 4 + quad) ^ swz(rb)) * 8)];
      }
#pragma unroll
      for (int fm = 0; fm < 4; ++fm)
#pragma unroll
        for (int fn = 0; fn < 4; ++fn)
          acc[fm][fn] = __builtin_amdgcn_mfma_f32_16x16x32_bf16(
              af[fm], bfr[fn], acc[fm][fn], 0, 0, 0);
    }
    __syncthreads();   // protect LDS before next stage
  }
}

__global__ __launch_bounds__(256, 2) void k_gemm(
    const bf16* __restrict__ A, const bf16* __restrict__ B,
    const float* __restrict__ bias, bf16* __restrict__ C,
    int N, int K, int relu)
{
  __shared__ __align__(16) bf16 As[128 * 64];
  __shared__ __align__(16) bf16 Bs[128 * 64];
  const int m0 = blockIdx.x * 128, n0 = blockIdx.y * 128;
  f32x4 acc[4][4] = {};
  gemm_core_async(A, B, As, Bs, acc, K, m0, n0, 0, K);

  const int lane15 = threadIdx.x & 15;
  const int quad   = (threadIdx.x & 63) >> 4;
  const int wave   = threadIdx.x >> 6;
  const int wm     = (wave & 1) << 6, wn = (wave >> 1) << 6;
#pragma unroll
  for (int fm = 0; fm < 4; ++fm)
#pragma unroll
    for (int fn = 0; fn < 4; ++fn) {
      const int col = n0 + wn + fn * 16 + lane15;
      const float bv = bias[col];
#pragma unroll
      for (int r = 0; r < 4; ++r) {
        const int row = m0 + wm + fm * 16 + quad * 4 + r;
        float v = acc[fm][fn][r] + bv;
        if (relu) v = fmaxf(v, 0.0f);
        C[(size_t)row * N + col] = (bf16)v;
      }
    }
}

// Fused QKV (same A, 3x weights via gridDim.z -> 384 blocks in flight).
__global__ __launch_bounds__(256, 2) void k_gemm_qkv(
    const bf16* __restrict__ h,
    const bf16* __restrict__ Wq, const bf16* __restrict__ Wk, const bf16* __restrict__ Wv,
    const float* __restrict__ bq, const float* __restrict__ bk, const float* __restrict__ bv,
    bf16* __restrict__ q, bf16* __restrict__ k, bf16* __restrict__ v)
{
  __shared__ __align__(16) bf16 As[128 * 64];
  __shared__ __align__(16) bf16 Bs[128 * 64];
  const bf16* B; const float* bias; bf16* C;
  if (blockIdx.z == 0)      { B = Wq; bias = bq; C = q; }
  else if (blockIdx.z == 1) { B = Wk; bias = bk; C = k; }
  else                      { B = Wv; bias = bv; C = v; }
  const int m0 = blockIdx.x * 128, n0 = blockIdx.y * 128;
  f32x4 acc[4][4] = {};
  gemm_core_async(h, B, As, Bs, acc, 512, m0, n0, 0, 512);

  const int lane15 = threadIdx.x & 15;
  const int quad   = (threadIdx.x & 63) >> 4;
  const int wave   = threadIdx.x >> 6;
  const int wm     = (wave & 1) << 6, wn = (wave >> 1) << 6;
#pragma unroll
  for (int fm = 0; fm < 4; ++fm)
#pragma unroll
    for (int fn = 0; fn < 4; ++fn) {
      const int col = n0 + wn + fn * 16 + lane15;
      const float bv = bias[col];
#pragma unroll
      for (int r = 0; r < 4; ++r) {
        const int row = m0 + wm + fm * 16 + quad * 4 + r;
        C[(size_t)row * 512 + col] = (bf16)(acc[fm][fn][r] + bv);
      }
    }
}

// Split-K GEMM -> f32 partials Cp[z][4096][N].
__global__ __launch_bounds__(256, 2) void k_gemm_sk(
    const bf16* __restrict__ A, const bf16* __restrict__ B,
    float* __restrict__ Cp, int N, int K, int Ksplit)
{
  __shared__ __align__(16) bf16 As[128 * 64];
  __shared__ __align__(16) bf16 Bs[128 * 64];
  const int m0 = blockIdx.x * 128, n0 = blockIdx.y * 128;
  const int kbeg = blockIdx.z * Ksplit;
  f32x4 acc[4][4] = {};
  gemm_core_async(A, B, As, Bs, acc, K, m0, n0, kbeg, kbeg + Ksplit);

  const int lane15 = threadIdx.x & 15;
  const int quad   = (threadIdx.x & 63) >> 4;
  const int wave   = threadIdx.x >> 6;
  const int wm     = (wave & 1) << 6, wn = (wave >> 1) << 6;
  float* Cz = Cp + (size_t)blockIdx.z * 4096 * N;
#pragma unroll
  for (int fm = 0; fm < 4; ++fm)
#pragma unroll
    for (int fn = 0; fn < 4; ++fn) {
      const int col = n0 + wn + fn * 16 + lane15;
#pragma unroll
      for (int r = 0; r < 4; ++r) {
        const int row = m0 + wm + fm * 16 + quad * 4 + r;
        Cz[(size_t)row * N + col] = acc[fm][fn][r];
      }
    }
}

// ---------------------------------------------------------------------------
// Pack adjacency (+self loops) into 64-bit mask words.
// ---------------------------------------------------------------------------
__global__ __launch_bounds__(256) void k_packmask(
    const int* __restrict__ adj, unsigned long long* __restrict__ mb)
{
  const int gw   = (int)((blockIdx.x * 256 + threadIdx.x) >> 6);
  const int lane = threadIdx.x & 63;
  const int a    = adj[(size_t)gw * 64 + lane];
  unsigned long long m = __ballot(a != 0);
  const int row = gw >> 6, wc = gw & 63;
  if ((row >> 6) == wc) m |= 1ull << (row & 63);
  if (lane == 0) mb[gw] = m;
}

// ---------------------------------------------------------------------------
// Transpose V: v[4096][512] -> vt[512][4096].
// ---------------------------------------------------------------------------
__global__ __launch_bounds__(256) void k_transpose_v(
    const bf16* __restrict__ v, bf16* __restrict__ vt)
{
  __shared__ __align__(16) bf16 T[64 * 72];
  const int r0 = blockIdx.x * 64;
  const int c0 = blockIdx.y * 64;
  const int tid = threadIdx.x;
#pragma unroll
  for (int rr = 0; rr < 2; ++rr) {
    int idx = rr * 256 + tid;
    int kr = idx >> 3, ch = (idx & 7) * 8;
    *(bf16x8*)&T[kr * 72 + ch] = *(const bf16x8*)&v[(size_t)(r0 + kr) * 512 + c0 + ch];
  }
  __syncthreads();
#pragma unroll
  for (int rr = 0; rr < 2; ++rr) {
    int idx = rr * 256 + tid;
    int cr = idx >> 3, ch = idx & 7;
    bf16x8 y;
#pragma unroll
    for (int j = 0; j < 8; ++j) y[j] = T[(ch * 8 + j) * 72 + cr];
    *(bf16x8*)&vt[(size_t)(c0 + cr) * 4096 + r0 + ch * 8] = y;
  }
}

// ---------------------------------------------------------------------------
// Flash attention, split-K x4, 32 q-rows per wave (block = 128 q-rows).
// Grid: 32 qt x 8 hd x 4 sp = 1024 blocks (4/CU). K/V LDS reads amortized
// over 2x MFMAs vs the 16-row version. No online max (bounded scores);
// l via ones-MFMA; P transits LDS bf16 (wave-private, no barrier needed —
// in-order LDS within a wave, validated round 4).
// ---------------------------------------------------------------------------
__global__ __launch_bounds__(256, 4) void k_attn(
    const bf16* __restrict__ Q, const bf16* __restrict__ Km,
    const bf16* __restrict__ Vt, const unsigned long long* __restrict__ mb,
    bf16* __restrict__ Opart, float* __restrict__ Lpart)
{
  __shared__ __align__(16) bf16 Ks[64 * 72];      // [key][dim]
  __shared__ __align__(16) bf16 Vs[64 * 72];      // [dim][key]
  __shared__ __align__(16) bf16 Plb[4][32 * 72];  // per-wave P (32 rows)

  const int tid    = threadIdx.x;
  const int wave   = tid >> 6;
  const int lane   = tid & 63;
  const int lane15 = lane & 15;
  const int quad   = lane >> 4;
  const int sp     = blockIdx.x & 3;
  const int hd     = (blockIdx.x >> 2) & 7;
  const int qt     = blockIdx.x >> 5;
  const int qrow   = qt * 128 + wave * 32;

  bf16x8 qf[2][2];
#pragma unroll
  for (int mt = 0; mt < 2; ++mt)
#pragma unroll
    for (int c = 0; c < 2; ++c)
      qf[mt][c] = *(const bf16x8*)&Q[(size_t)(qrow + mt * 16 + lane15) * 512 +
                                     hd * 64 + c * 32 + quad * 8];

  bf16x8 ones;
#pragma unroll
  for (int j = 0; j < 8; ++j) ones[j] = (bf16)1.0f;

  f32x4 o[2][4] = {};
  f32x4 la[2]   = {};

  for (int kt = sp * 16; kt < sp * 16 + 16; ++kt) {
    const int kb = kt * 64;
#pragma unroll
    for (int rr = 0; rr < 2; ++rr) {
      int idx = rr * 256 + tid;
      int a = idx >> 3, ch = (idx & 7) * 8;
      *(bf16x8*)&Ks[a * 72 + ch] = *(const bf16x8*)&Km[(size_t)(kb + a) * 512 + hd * 64 + ch];
      *(bf16x8*)&Vs[a * 72 + ch] = *(const bf16x8*)&Vt[(size_t)(hd * 64 + a) * 4096 + kb + ch];
    }
    __syncthreads();

    unsigned long long mw[2][4];
#pragma unroll
    for (int mt = 0; mt < 2; ++mt)
#pragma unroll
      for (int r = 0; r < 4; ++r)
        mw[mt][r] = mb[(size_t)(qrow + mt * 16 + quad * 4 + r) * 64 + kt] >> lane15;

    // S = Q K^T (32 q x 64 keys); p = mask ? exp(s/8) : 0 -> Plb
#pragma unroll
    for (int g = 0; g < 4; ++g) {
      bf16x8 k0f = *(const bf16x8*)&Ks[(g * 16 + lane15) * 72 + quad * 8];
      bf16x8 k1f = *(const bf16x8*)&Ks[(g * 16 + lane15) * 72 + 32 + quad * 8];
#pragma unroll
      for (int mt = 0; mt < 2; ++mt) {
        f32x4 s = {};
        s = __builtin_amdgcn_mfma_f32_16x16x32_bf16(qf[mt][0], k0f, s, 0, 0, 0);
        s = __builtin_amdgcn_mfma_f32_16x16x32_bf16(qf[mt][1], k1f, s, 0, 0, 0);
#pragma unroll
        for (int r = 0; r < 4; ++r) {
          const bool ok = ((mw[mt][r] >> (g * 16)) & 1ull) != 0;
          const float p = ok ? __expf(s[r] * 0.125f) : 0.0f;
          Plb[wave][(mt * 16 + quad * 4 + r) * 72 + g * 16 + lane15] = (bf16)p;
        }
      }
    }

    // O += P V ; l += P 1   (V-frags shared across both m-tiles)
#pragma unroll
    for (int c2 = 0; c2 < 2; ++c2) {
      bf16x8 vf[4];
#pragma unroll
      for (int g2 = 0; g2 < 4; ++g2)
        vf[g2] = *(const bf16x8*)&Vs[(g2 * 16 + lane15) * 72 + c2 * 32 + quad * 8];
#pragma unroll
      for (int mt = 0; mt < 2; ++mt) {
        bf16x8 pa = *(const bf16x8*)&Plb[wave][(mt * 16 + lane15) * 72 + c2 * 32 + quad * 8];
        la[mt] = __builtin_amdgcn_mfma_f32_16x16x32_bf16(pa, ones, la[mt], 0, 0, 0);
#pragma unroll
        for (int g2 = 0; g2 < 4; ++g2)
          o[mt][g2] = __builtin_amdgcn_mfma_f32_16x16x32_bf16(pa, vf[g2], o[mt][g2], 0, 0, 0);
      }
    }
    __syncthreads();
  }

  bf16* Oz = Opart + (size_t)sp * 4096 * 512;
#pragma unroll
  for (int mt = 0; mt < 2; ++mt) {
#pragma unroll
    for (int g2 = 0; g2 < 4; ++g2)
#pragma unroll
      for (int r = 0; r < 4; ++r) {
        const int row = qrow + mt * 16 + quad * 4 + r;
        Oz[(size_t)row * 512 + hd * 64 + g2 * 16 + lane15] = (bf16)o[mt][g2][r];
      }
    if (lane15 == 0) {
#pragma unroll
      for (int r = 0; r < 4; ++r)
        Lpart[sp * 32768 + (qrow + mt * 16 + quad * 4 + r) * 8 + hd] = la[mt][r];
    }
  }
}

// Combine attention partials: ctx = (sum_s O_s) / (sum_s l_s).
__global__ __launch_bounds__(256) void k_attn_combine(
    const bf16* __restrict__ Opart, const float* __restrict__ Lpart,
    bf16* __restrict__ ctx)
{
  const int g = blockIdx.x * 256 + threadIdx.x;
  const size_t base = (size_t)g * 8;
  const int row = g >> 6;
  const int hd  = (g & 63) >> 3;
  float acc[8] = {};
  float l = 0.0f;
#pragma unroll
  for (int s = 0; s < 4; ++s) {
    bf16x8 ov = *(const bf16x8*)&Opart[(size_t)s * 4096 * 512 + base];
#pragma unroll
    for (int j = 0; j < 8; ++j) acc[j] += (float)ov[j];
    l += Lpart[s * 32768 + row * 8 + hd];
  }
  const float rl = 1.0f / l;
  bf16x8 y;
#pragma unroll
  for (int j = 0; j < 8; ++j) y[j] = (bf16)(acc[j] * rl);
  *(bf16x8*)(ctx + base) = y;
}

// ---------------------------------------------------------------------------
// Fused: split-K combine + bias + residual + LayerNorm. N=512 fixed.
// x bf16; Cp = 2 f32 partial planes; bias/gam/bet raw fp32.
// ---------------------------------------------------------------------------
template <int F32OUT>
__global__ __launch_bounds__(256) void k_addln_sk(
    const bf16* __restrict__ x, const float* __restrict__ Cp,
    const float* __restrict__ bias,
    const float* __restrict__ gam, const float* __restrict__ bet,
    void* __restrict__ out)
{
  const int wave = threadIdx.x >> 6, lane = threadIdx.x & 63;
  const int row  = blockIdx.x * 4 + wave;
  const size_t base = (size_t)row * 512 + lane * 8;
  const int col = lane * 8;
  bf16x8 xv = *(const bf16x8*)(x + base);
  const float* p0 = Cp + base;
  const float* p1 = Cp + (size_t)4096 * 512 + base;
  f32x4 a0 = *(const f32x4*)p0, a1 = *(const f32x4*)(p0 + 4);
  f32x4 b0 = *(const f32x4*)p1, b1 = *(const f32x4*)(p1 + 4);
  f32x4 c0 = *(const f32x4*)(bias + col), c1 = *(const f32x4*)(bias + col + 4);
  float v[8], s = 0.0f, s2 = 0.0f;
#pragma unroll
  for (int j = 0; j < 4; ++j) {
    v[j]     = (float)xv[j]     + a0[j] + b0[j] + c0[j];
    v[4 + j] = (float)xv[4 + j] + a1[j] + b1[j] + c1[j];
  }
#pragma unroll
  for (int j = 0; j < 8; ++j) { s += v[j]; s2 += v[j] * v[j]; }
#pragma unroll
  for (int d = 1; d < 64; d <<= 1) { s += __shfl_xor(s, d, 64); s2 += __shfl_xor(s2, d, 64); }
  const float mu  = s * (1.0f / 512.0f);
  const float var = s2 * (1.0f / 512.0f) - mu * mu;
  const float rs  = rsqrtf(var + 1e-5f);
  f32x4 g0 = *(const f32x4*)(gam + col), g1 = *(const f32x4*)(gam + col + 4);
  f32x4 e0 = *(const f32x4*)(bet + col), e1 = *(const f32x4*)(bet + col + 4);
  if (F32OUT) {
    float* o = (float*)out + base;
#pragma unroll
    for (int j = 0; j < 4; ++j) {
      o[j]     = ((v[j] - mu) * rs) * g0[j] + e0[j];
      o[4 + j] = ((v[4 + j] - mu) * rs) * g1[j] + e1[j];
    }
  } else {
    bf16x8 ov;
#pragma unroll
    for (int j = 0; j < 4; ++j) {
      ov[j]     = (bf16)(((v[j] - mu) * rs) * g0[j] + e0[j]);
      ov[4 + j] = (bf16)(((v[4 + j] - mu) * rs) * g1[j] + e1[j]);
    }
    *(bf16x8*)((bf16*)out + base) = ov;
  }
}

// ---------------------------------------------------------------------------
extern "C" void kernel_launch(void* const* d_in, const int* in_sizes, int n_in,
                              void* d_out, int out_size, void* d_ws, size_t ws_size,
                              hipStream_t stream)
{
  const int*   adj = (const int*)  d_in[1];
  const float* bq  = (const float*)d_in[3];
  const float* bk  = (const float*)d_in[5];
  const float* bv  = (const float*)d_in[7];
  const float* bo  = (const float*)d_in[9];
  const float* b1  = (const float*)d_in[11];
  const float* b2  = (const float*)d_in[13];
  const float* g1  = (const float*)d_in[14];
  const float* be1 = (const float*)d_in[15];
  const float* g2  = (const float*)d_in[16];
  const float* be2 = (const float*)d_in[17];

  char* ws = (char*)d_ws;
  const size_t MB = 1024 * 1024;

  // --- bf16 arena ------------------------------------------------------------
  bf16* hb  = (bf16*)(ws + 0 * MB);                  // 4 MB
  bf16* Wqb = (bf16*)(ws + 4 * MB);
  bf16* Wkb = (bf16*)(ws + 4 * MB + 512 * 1024);
  bf16* Wvb = (bf16*)(ws + 5 * MB);
  bf16* Wob = (bf16*)(ws + 5 * MB + 512 * 1024);
  bf16* W1b = (bf16*)(ws + 6 * MB);                  // 2 MB
  bf16* W2b = (bf16*)(ws + 8 * MB);                  // 2 MB

  // --- intermediates (lifetime-packed) --------------------------------------
  bf16* q    = (bf16*)(ws + 12 * MB);   // dead after attn
  bf16* k    = (bf16*)(ws + 16 * MB);   // dead after attn
  bf16* v    = (bf16*)(ws + 20 * MB);   // dead after transpose
  bf16* vt   = (bf16*)(ws + 24 * MB);   // dead after attn
  unsigned long long* mbits = (unsigned long long*)(ws + 28 * MB); // 2 MB
  bf16* ctx  = (bf16*)(ws + 30 * MB);   // dead after Wo sk-gemm
  bf16*  Opart = (bf16*)(ws + 34 * MB); // 16 MB, dead after attn_combine
  float* Lpart = (float*)(ws + 50 * MB);// 0.5 MB
  float* skP   = (float*)(ws + 34 * MB);// 16 MB f32 partials (over Opart)
  bf16* h1   = (bf16*)(ws + 12 * MB);   // over q (dead)
  bf16* ff1  = (bf16*)(ws + 16 * MB);   // 16 MB over k,v,vt,mbits (all dead)
  // peak ws use: 50.5 MB

  // --- batched cast (7 tensors) ---------------------------------------------
  CastArgs ca;
  const int srcIdx[7] = {0, 2, 4, 6, 8, 10, 12};
  bf16* dsts[7] = {hb, Wqb, Wkb, Wvb, Wob, W1b, W2b};
  int cum = 0;
  for (int t = 0; t < 7; ++t) {
    ca.src[t] = (const float*)d_in[srcIdx[t]];
    ca.dst[t] = dsts[t];
    ca.cum[t] = cum;
    cum += in_sizes[srcIdx[t]] / 8;
  }
  ca.cum[7] = cum;

  const dim3 blk(256);
  k_cast<<<dim3((cum + 255) / 256), blk, 0, stream>>>(ca, cum);

  // 1. QKV projections (async-staged, 384 blocks)
  k_gemm_qkv<<<dim3(32, 4, 3), blk, 0, stream>>>(hb, Wqb, Wkb, Wvb, bq, bk, bv, q, k, v);
  // 2. transpose V
  k_transpose_v<<<dim3(64, 8), blk, 0, stream>>>(v, vt);
  // 3. pack adjacency(+I)
  k_packmask<<<dim3(65536), blk, 0, stream>>>(adj, mbits);
  // 4. flash attention, split-K x4, 32 q-rows/wave (1024 blocks) + combine
  k_attn<<<dim3(1024), blk, 0, stream>>>(q, k, vt, mbits, Opart, Lpart);
  k_attn_combine<<<dim3(1024), blk, 0, stream>>>(Opart, Lpart, ctx);
  // 5. output projection split-K x2 -> fused combine+LN1 -> h1
  k_gemm_sk<<<dim3(32, 4, 2), blk, 0, stream>>>(ctx, Wob, skP, 512, 512, 256);
  k_addln_sk<0><<<dim3(1024), blk, 0, stream>>>(hb, skP, bo, g1, be1, (void*)h1);
  // 6. ff1 = relu(h1 @ W1^T + b1)
  k_gemm<<<dim3(32, 16), blk, 0, stream>>>(h1, W1b, b1, ff1, 2048, 512, 1);
  // 7. ff2 split-K x2 -> fused combine+LN2 -> d_out (fp32)
  k_gemm_sk<<<dim3(32, 4, 2), blk, 0, stream>>>(ff1, W2b, skP, 512, 2048, 1024);
  k_addln_sk<1><<<dim3(1024), blk, 0, stream>>>(h1, skP, b2, g2, be2, d_out);
}

// Round 7
// 290.456 us; speedup vs baseline: 1.3480x; 1.0734x over previous
//
#include <hip/hip_runtime.h>
#include <stdint.h>
#include <stddef.h>

typedef __bf16 bf16;
typedef __bf16 bf16x8 __attribute__((ext_vector_type(8)));
typedef float  f32x4  __attribute__((ext_vector_type(4)));

typedef __attribute__((address_space(3))) void       lds_void;
typedef __attribute__((address_space(1))) const void gbl_cvoid;

#define ASYNC_CP16(g, l) \
  __builtin_amdgcn_global_load_lds((gbl_cvoid*)(g), (lds_void*)(l), 16, 0, 0)

// chunk swizzle: spreads b128 fragment reads across banks (verified round 5)
__device__ __forceinline__ int swz(int r) { return (r & 7) ^ ((r & 8) >> 1); }

// ---------------------------------------------------------------------------
// Prep kernel: blocks [0,65536) pack adjacency(+I) into 64-bit masks;
// blocks [65536, ...) do the batched fp32->bf16 cast.
// ---------------------------------------------------------------------------
struct CastArgs {
  const float* src[7];
  bf16*        dst[7];
  int          cum[8];
};

__global__ __launch_bounds__(256) void k_prep(
    const int* __restrict__ adj, unsigned long long* __restrict__ mb,
    CastArgs a, int total8)
{
  const int bid = blockIdx.x;
  if (bid < 65536) {
    const int gw   = (int)(((unsigned)bid * 256 + threadIdx.x) >> 6);
    const int lane = threadIdx.x & 63;
    const int av   = adj[(size_t)gw * 64 + lane];
    unsigned long long m = __ballot(av != 0);
    const int row = gw >> 6, wc = gw & 63;
    if ((row >> 6) == wc) m |= 1ull << (row & 63);
    if (lane == 0) mb[gw] = m;
  } else {
    const int g = (bid - 65536) * 256 + threadIdx.x;
    if (g >= total8) return;
    int t = 0;
    while (a.cum[t + 1] <= g) ++t;
    const int i = g - a.cum[t];
    const float4* s = (const float4*)(a.src[t]) + (size_t)i * 2;
    const float4 x0 = s[0], x1 = s[1];
    bf16x8 y;
    y[0] = (bf16)x0.x; y[1] = (bf16)x0.y; y[2] = (bf16)x0.z; y[3] = (bf16)x0.w;
    y[4] = (bf16)x1.x; y[5] = (bf16)x1.y; y[6] = (bf16)x1.z; y[7] = (bf16)x1.w;
    *(bf16x8*)(a.dst[t] + (size_t)i * 8) = y;
  }
}

// ---------------------------------------------------------------------------
// Async-staged GEMM core, templated on m-tile (MT=128: 2x2 waves, 4x4 frags;
// MT=64: 1x4 waves, 4x2 frags). N-tile fixed 128, BK=64.
// ---------------------------------------------------------------------------
template <int MT>
__device__ __forceinline__ void gemm_core_async(
    const bf16* __restrict__ A, const bf16* __restrict__ B,
    bf16* As, bf16* Bs, f32x4 (&acc)[4][(MT == 128) ? 4 : 2],
    int K, int m0, int n0, int kbeg, int kend)
{
  constexpr int FN = (MT == 128) ? 4 : 2;
  constexpr int IA = MT / 32;             // A staging wave-instrs per wave
  const int tid    = threadIdx.x;
  const int lane   = tid & 63;
  const int wave   = tid >> 6;
  const int lane15 = lane & 15;
  const int quad   = lane >> 4;
  const int wm     = (MT == 128) ? ((wave & 1) << 6) : 0;
  const int wn     = (MT == 128) ? ((wave >> 1) << 6) : (wave << 5);

  int srA[IA], soA[IA], srB[4], soB[4];
#pragma unroll
  for (int i = 0; i < IA; ++i) {
    int c  = ((wave * IA + i) << 6) + lane;
    srA[i] = c >> 3;
    soA[i] = ((c & 7) ^ swz(srA[i])) * 8;
  }
#pragma unroll
  for (int i = 0; i < 4; ++i) {
    int c  = ((wave * 4 + i) << 6) + lane;
    srB[i] = c >> 3;
    soB[i] = ((c & 7) ^ swz(srB[i])) * 8;
  }

  const bf16* Ab = A + (size_t)m0 * K;
  const bf16* Bb = B + (size_t)n0 * K;

  for (int k0 = kbeg; k0 < kend; k0 += 64) {
#pragma unroll
    for (int i = 0; i < IA; ++i)
      ASYNC_CP16(Ab + (size_t)srA[i] * K + k0 + soA[i], &As[(wave * IA + i) * 512]);
#pragma unroll
    for (int i = 0; i < 4; ++i)
      ASYNC_CP16(Bb + (size_t)srB[i] * K + k0 + soB[i], &Bs[(wave * 4 + i) * 512]);
    __syncthreads();

#pragma unroll
    for (int kk = 0; kk < 2; ++kk) {
      bf16x8 af[4], bfr[FN];
#pragma unroll
      for (int f = 0; f < 4; ++f) {
        const int ra = wm + f * 16 + lane15;
        af[f] = *(const bf16x8*)&As[ra * 64 + (((kk * 4 + quad) ^ swz(ra)) * 8)];
      }
#pragma unroll
      for (int f = 0; f < FN; ++f) {
        const int rb = wn + f * 16 + lane15;
        bfr[f] = *(const bf16x8*)&Bs[rb * 64 + (((kk * 4 + quad) ^ swz(rb)) * 8)];
      }
#pragma unroll
      for (int fm = 0; fm < 4; ++fm)
#pragma unroll
        for (int fn = 0; fn < FN; ++fn)
          acc[fm][fn] = __builtin_amdgcn_mfma_f32_16x16x32_bf16(
              af[fm], bfr[fn], acc[fm][fn], 0, 0, 0);
    }
    __syncthreads();
  }
}

// FF1: MT=128 full-K GEMM + bias + relu.
__global__ __launch_bounds__(256, 2) void k_gemm(
    const bf16* __restrict__ A, const bf16* __restrict__ B,
    const float* __restrict__ bias, bf16* __restrict__ C,
    int N, int K, int relu)
{
  __shared__ __align__(16) bf16 As[128 * 64];
  __shared__ __align__(16) bf16 Bs[128 * 64];
  const int m0 = blockIdx.x * 128, n0 = blockIdx.y * 128;
  f32x4 acc[4][4] = {};
  gemm_core_async<128>(A, B, As, Bs, acc, K, m0, n0, 0, K);

  const int lane15 = threadIdx.x & 15;
  const int quad   = (threadIdx.x & 63) >> 4;
  const int wave   = threadIdx.x >> 6;
  const int wm = (wave & 1) << 6, wn = (wave >> 1) << 6;
#pragma unroll
  for (int fm = 0; fm < 4; ++fm)
#pragma unroll
    for (int fn = 0; fn < 4; ++fn) {
      const int col = n0 + wn + fn * 16 + lane15;
      const float bv = bias[col];
#pragma unroll
      for (int r = 0; r < 4; ++r) {
        const int row = m0 + wm + fm * 16 + quad * 4 + r;
        float v = acc[fm][fn][r] + bv;
        if (relu) v = fmaxf(v, 0.0f);
        C[(size_t)row * N + col] = (bf16)v;
      }
    }
}

// QKV: one GEMM over concat weights [1536,512] (rows 0-511 Wq, 512-1023 Wk,
// 1024-1535 Wv). MT=64 -> grid (64,12) = 768 blocks. V-projection blocks
// write vt (transposed) via an LDS transpose in the epilogue.
__global__ __launch_bounds__(256, 4) void k_gemm_qkv(
    const bf16* __restrict__ h, const bf16* __restrict__ Wcat,
    const float* __restrict__ bq, const float* __restrict__ bk,
    const float* __restrict__ bv,
    bf16* __restrict__ q, bf16* __restrict__ k, bf16* __restrict__ vt)
{
  __shared__ __align__(16) bf16 SM[64 * 64 + 128 * 64];   // 24 KB
  bf16* As = SM;
  bf16* Bs = SM + 64 * 64;
  const int m0 = blockIdx.x * 64, n0 = blockIdx.y * 128;
  f32x4 acc[4][2] = {};
  gemm_core_async<64>(h, Wcat, As, Bs, acc, 512, m0, n0, 0, 512);

  const int lane15 = threadIdx.x & 15;
  const int quad   = (threadIdx.x & 63) >> 4;
  const int wave   = threadIdx.x >> 6;
  const int wn     = wave << 5;
  const int proj   = n0 >> 9;                  // 0=q 1=k 2=v
  const int ncol0  = n0 & 511;
  const float* bias = (proj == 0) ? bq : (proj == 1) ? bk : bv;

  if (proj < 2) {
    bf16* C = proj ? k : q;
#pragma unroll
    for (int fm = 0; fm < 4; ++fm)
#pragma unroll
      for (int fn = 0; fn < 2; ++fn) {
        const int col = ncol0 + wn + fn * 16 + lane15;
        const float bvv = bias[col];
#pragma unroll
        for (int r = 0; r < 4; ++r) {
          const int row = m0 + fm * 16 + quad * 4 + r;
          C[(size_t)row * 512 + col] = (bf16)(acc[fm][fn][r] + bvv);
        }
      }
  } else {
    // transpose 64(tokens) x 128(vdims) through LDS -> vt[vdim][token]
    __syncthreads();   // K-loop LDS dead
#pragma unroll
    for (int fm = 0; fm < 4; ++fm)
#pragma unroll
      for (int fn = 0; fn < 2; ++fn) {
        const int colL = wn + fn * 16 + lane15;
        const float bvv = bias[ncol0 + colL];
#pragma unroll
        for (int r = 0; r < 4; ++r) {
          const int rowL = fm * 16 + quad * 4 + r;
          SM[colL * 72 + rowL] = (bf16)(acc[fm][fn][r] + bvv);
        }
      }
    __syncthreads();
#pragma unroll
    for (int i = 0; i < 4; ++i) {
      const int c = i * 256 + threadIdx.x;     // 1024 chunks
      const int colL = c >> 3, rw = (c & 7) * 8;
      *(bf16x8*)&vt[(size_t)(ncol0 + colL) * 4096 + m0 + rw] =
          *(const bf16x8*)&SM[colL * 72 + rw];
    }
  }
}

// Split-K GEMM (MT=64) -> f32 partials Cp[z][4096][N].
__global__ __launch_bounds__(256, 4) void k_gemm_sk(
    const bf16* __restrict__ A, const bf16* __restrict__ B,
    float* __restrict__ Cp, int N, int K, int Ksplit)
{
  __shared__ __align__(16) bf16 As[64 * 64];
  __shared__ __align__(16) bf16 Bs[128 * 64];
  const int m0 = blockIdx.x * 64, n0 = blockIdx.y * 128;
  const int kbeg = blockIdx.z * Ksplit;
  f32x4 acc[4][2] = {};
  gemm_core_async<64>(A, B, As, Bs, acc, K, m0, n0, kbeg, kbeg + Ksplit);

  const int lane15 = threadIdx.x & 15;
  const int quad   = (threadIdx.x & 63) >> 4;
  const int wave   = threadIdx.x >> 6;
  const int wn     = wave << 5;
  float* Cz = Cp + (size_t)blockIdx.z * 4096 * N;
#pragma unroll
  for (int fm = 0; fm < 4; ++fm)
#pragma unroll
    for (int fn = 0; fn < 2; ++fn) {
      const int col = n0 + wn + fn * 16 + lane15;
#pragma unroll
      for (int r = 0; r < 4; ++r) {
        const int row = m0 + fm * 16 + quad * 4 + r;
        Cz[(size_t)row * N + col] = acc[fm][fn][r];
      }
    }
}

// ---------------------------------------------------------------------------
// Flash attention, split-K x4, 32 q-rows/wave, async K/V staging (swizzled,
// no pad). No online max (bounded scores); l via ones-MFMA; P round-trips
// LDS bf16 (wave-private).
// ---------------------------------------------------------------------------
__global__ __launch_bounds__(256, 4) void k_attn(
    const bf16* __restrict__ Q, const bf16* __restrict__ Km,
    const bf16* __restrict__ Vt, const unsigned long long* __restrict__ mb,
    bf16* __restrict__ Opart, float* __restrict__ Lpart)
{
  __shared__ __align__(16) bf16 Ks[64 * 64];
  __shared__ __align__(16) bf16 Vs[64 * 64];
  __shared__ __align__(16) bf16 Plb[4][32 * 72];

  const int tid    = threadIdx.x;
  const int wave   = tid >> 6;
  const int lane   = tid & 63;
  const int lane15 = lane & 15;
  const int quad   = lane >> 4;
  const int sp     = blockIdx.x & 3;
  const int hd     = (blockIdx.x >> 2) & 7;
  const int qt     = blockIdx.x >> 5;
  const int qrow   = qt * 128 + wave * 32;

  bf16x8 qf[2][2];
#pragma unroll
  for (int mt = 0; mt < 2; ++mt)
#pragma unroll
    for (int c = 0; c < 2; ++c)
      qf[mt][c] = *(const bf16x8*)&Q[(size_t)(qrow + mt * 16 + lane15) * 512 +
                                     hd * 64 + c * 32 + quad * 8];

  // async staging bases (chunk geometry identical to GEMM core, 2 instrs/wave)
  int srK[2], soK[2];
#pragma unroll
  for (int i = 0; i < 2; ++i) {
    int c  = ((wave * 2 + i) << 6) + lane;
    srK[i] = c >> 3;
    soK[i] = ((c & 7) ^ swz(srK[i])) * 8;
  }
  const bf16* KmB[2] = {
      Km + (size_t)srK[0] * 512 + hd * 64 + soK[0],
      Km + (size_t)srK[1] * 512 + hd * 64 + soK[1]};
  const bf16* VtB[2] = {
      Vt + (size_t)(hd * 64 + srK[0]) * 4096 + soK[0],
      Vt + (size_t)(hd * 64 + srK[1]) * 4096 + soK[1]};

  bf16x8 ones;
#pragma unroll
  for (int j = 0; j < 8; ++j) ones[j] = (bf16)1.0f;

  f32x4 o[2][4] = {};
  f32x4 la[2]   = {};

  for (int kt = sp * 16; kt < sp * 16 + 16; ++kt) {
    const int kb = kt * 64;
#pragma unroll
    for (int i = 0; i < 2; ++i) {
      ASYNC_CP16(KmB[i] + (size_t)kb * 512, &Ks[(wave * 2 + i) * 512]);
      ASYNC_CP16(VtB[i] + kb,               &Vs[(wave * 2 + i) * 512]);
    }
    __syncthreads();

    unsigned long long mw[2][4];
#pragma unroll
    for (int mt = 0; mt < 2; ++mt)
#pragma unroll
      for (int r = 0; r < 4; ++r)
        mw[mt][r] = mb[(size_t)(qrow + mt * 16 + quad * 4 + r) * 64 + kt] >> lane15;

#pragma unroll
    for (int g = 0; g < 4; ++g) {
      const int row = g * 16 + lane15;
      bf16x8 k0f = *(const bf16x8*)&Ks[row * 64 + ((quad       ^ swz(row)) * 8)];
      bf16x8 k1f = *(const bf16x8*)&Ks[row * 64 + (((4 + quad) ^ swz(row)) * 8)];
#pragma unroll
      for (int mt = 0; mt < 2; ++mt) {
        f32x4 s = {};
        s = __builtin_amdgcn_mfma_f32_16x16x32_bf16(qf[mt][0], k0f, s, 0, 0, 0);
        s = __builtin_amdgcn_mfma_f32_16x16x32_bf16(qf[mt][1], k1f, s, 0, 0, 0);
#pragma unroll
        for (int r = 0; r < 4; ++r) {
          const bool ok = ((mw[mt][r] >> (g * 16)) & 1ull) != 0;
          const float p = ok ? __expf(s[r] * 0.125f) : 0.0f;
          Plb[wave][(mt * 16 + quad * 4 + r) * 72 + g * 16 + lane15] = (bf16)p;
        }
      }
    }

#pragma unroll
    for (int c2 = 0; c2 < 2; ++c2) {
      bf16x8 vf[4];
#pragma unroll
      for (int g2 = 0; g2 < 4; ++g2) {
        const int row = g2 * 16 + lane15;
        vf[g2] = *(const bf16x8*)&Vs[row * 64 + (((c2 * 4 + quad) ^ swz(row)) * 8)];
      }
#pragma unroll
      for (int mt = 0; mt < 2; ++mt) {
        bf16x8 pa = *(const bf16x8*)&Plb[wave][(mt * 16 + lane15) * 72 + c2 * 32 + quad * 8];
        la[mt] = __builtin_amdgcn_mfma_f32_16x16x32_bf16(pa, ones, la[mt], 0, 0, 0);
#pragma unroll
        for (int g2 = 0; g2 < 4; ++g2)
          o[mt][g2] = __builtin_amdgcn_mfma_f32_16x16x32_bf16(pa, vf[g2], o[mt][g2], 0, 0, 0);
      }
    }
    __syncthreads();
  }

  bf16* Oz = Opart + (size_t)sp * 4096 * 512;
#pragma unroll
  for (int mt = 0; mt < 2; ++mt) {
#pragma unroll
    for (int g2 = 0; g2 < 4; ++g2)
#pragma unroll
      for (int r = 0; r < 4; ++r) {
        const int row = qrow + mt * 16 + quad * 4 + r;
        Oz[(size_t)row * 512 + hd * 64 + g2 * 16 + lane15] = (bf16)o[mt][g2][r];
      }
    if (lane15 == 0) {
#pragma unroll
      for (int r = 0; r < 4; ++r)
        Lpart[sp * 32768 + (qrow + mt * 16 + quad * 4 + r) * 8 + hd] = la[mt][r];
    }
  }
}

// Combine attention partials: ctx = (sum_s O_s) / (sum_s l_s).
__global__ __launch_bounds__(256) void k_attn_combine(
    const bf16* __restrict__ Opart, const float* __restrict__ Lpart,
    bf16* __restrict__ ctx)
{
  const int g = blockIdx.x * 256 + threadIdx.x;
  const size_t base = (size_t)g * 8;
  const int row = g >> 6;
  const int hd  = (g & 63) >> 3;
  float acc[8] = {};
  float l = 0.0f;
#pragma unroll
  for (int s = 0; s < 4; ++s) {
    bf16x8 ov = *(const bf16x8*)&Opart[(size_t)s * 4096 * 512 + base];
#pragma unroll
    for (int j = 0; j < 8; ++j) acc[j] += (float)ov[j];
    l += Lpart[s * 32768 + row * 8 + hd];
  }
  const float rl = 1.0f / l;
  bf16x8 y;
#pragma unroll
  for (int j = 0; j < 8; ++j) y[j] = (bf16)(acc[j] * rl);
  *(bf16x8*)(ctx + base) = y;
}

// ---------------------------------------------------------------------------
// Fused: split-K combine + bias + residual + LayerNorm. N=512 fixed.
// ---------------------------------------------------------------------------
template <int F32OUT>
__global__ __launch_bounds__(256) void k_addln_sk(
    const bf16* __restrict__ x, const float* __restrict__ Cp,
    const float* __restrict__ bias,
    const float* __restrict__ gam, const float* __restrict__ bet,
    void* __restrict__ out)
{
  const int wave = threadIdx.x >> 6, lane = threadIdx.x & 63;
  const int row  = blockIdx.x * 4 + wave;
  const size_t base = (size_t)row * 512 + lane * 8;
  const int col = lane * 8;
  bf16x8 xv = *(const bf16x8*)(x + base);
  const float* p0 = Cp + base;
  const float* p1 = Cp + (size_t)4096 * 512 + base;
  f32x4 a0 = *(const f32x4*)p0, a1 = *(const f32x4*)(p0 + 4);
  f32x4 b0 = *(const f32x4*)p1, b1 = *(const f32x4*)(p1 + 4);
  f32x4 c0 = *(const f32x4*)(bias + col), c1 = *(const f32x4*)(bias + col + 4);
  float v[8], s = 0.0f, s2 = 0.0f;
#pragma unroll
  for (int j = 0; j < 4; ++j) {
    v[j]     = (float)xv[j]     + a0[j] + b0[j] + c0[j];
    v[4 + j] = (float)xv[4 + j] + a1[j] + b1[j] + c1[j];
  }
#pragma unroll
  for (int j = 0; j < 8; ++j) { s += v[j]; s2 += v[j] * v[j]; }
#pragma unroll
  for (int d = 1; d < 64; d <<= 1) { s += __shfl_xor(s, d, 64); s2 += __shfl_xor(s2, d, 64); }
  const float mu  = s * (1.0f / 512.0f);
  const float var = s2 * (1.0f / 512.0f) - mu * mu;
  const float rs  = rsqrtf(var + 1e-5f);
  f32x4 g0 = *(const f32x4*)(gam + col), g1 = *(const f32x4*)(gam + col + 4);
  f32x4 e0 = *(const f32x4*)(bet + col), e1 = *(const f32x4*)(bet + col + 4);
  if (F32OUT) {
    float* o = (float*)out + base;
#pragma unroll
    for (int j = 0; j < 4; ++j) {
      o[j]     = ((v[j] - mu) * rs) * g0[j] + e0[j];
      o[4 + j] = ((v[4 + j] - mu) * rs) * g1[j] + e1[j];
    }
  } else {
    bf16x8 ov;
#pragma unroll
    for (int j = 0; j < 4; ++j) {
      ov[j]     = (bf16)(((v[j] - mu) * rs) * g0[j] + e0[j]);
      ov[4 + j] = (bf16)(((v[4 + j] - mu) * rs) * g1[j] + e1[j]);
    }
    *(bf16x8*)((bf16*)out + base) = ov;
  }
}

// ---------------------------------------------------------------------------
extern "C" void kernel_launch(void* const* d_in, const int* in_sizes, int n_in,
                              void* d_out, int out_size, void* d_ws, size_t ws_size,
                              hipStream_t stream)
{
  const int*   adj = (const int*)  d_in[1];
  const float* bq  = (const float*)d_in[3];
  const float* bk  = (const float*)d_in[5];
  const float* bv  = (const float*)d_in[7];
  const float* bo  = (const float*)d_in[9];
  const float* b1  = (const float*)d_in[11];
  const float* b2  = (const float*)d_in[13];
  const float* g1  = (const float*)d_in[14];
  const float* be1 = (const float*)d_in[15];
  const float* g2  = (const float*)d_in[16];
  const float* be2 = (const float*)d_in[17];

  char* ws = (char*)d_ws;
  const size_t MB = 1024 * 1024;

  // bf16 arena. Wq/Wk/Wv are contiguous, forming the concat [1536,512] matrix.
  bf16* hb  = (bf16*)(ws + 0 * MB);                  // 4 MB
  bf16* Wqb = (bf16*)(ws + 4 * MB);                  // concat base
  bf16* Wkb = (bf16*)(ws + 4 * MB + 512 * 1024);
  bf16* Wvb = (bf16*)(ws + 5 * MB);
  bf16* Wob = (bf16*)(ws + 5 * MB + 512 * 1024);
  bf16* W1b = (bf16*)(ws + 6 * MB);                  // 2 MB
  bf16* W2b = (bf16*)(ws + 8 * MB);                  // 2 MB

  // intermediates (lifetime-packed)
  bf16* q    = (bf16*)(ws + 12 * MB);   // dead after attn
  bf16* k    = (bf16*)(ws + 16 * MB);   // dead after attn
  bf16* vt   = (bf16*)(ws + 24 * MB);   // dead after attn
  unsigned long long* mbits = (unsigned long long*)(ws + 28 * MB); // 2 MB
  bf16* ctx  = (bf16*)(ws + 30 * MB);   // dead after Wo sk-gemm
  bf16*  Opart = (bf16*)(ws + 34 * MB); // 16 MB, dead after attn_combine
  float* Lpart = (float*)(ws + 50 * MB);// 0.5 MB
  float* skP   = (float*)(ws + 34 * MB);// 16 MB f32 partials (over Opart)
  bf16* h1   = (bf16*)(ws + 12 * MB);   // over q (dead)
  bf16* ff1  = (bf16*)(ws + 16 * MB);   // 16 MB over k,vt,mbits,ctx (all dead)

  // cast args
  CastArgs ca;
  const int srcIdx[7] = {0, 2, 4, 6, 8, 10, 12};
  bf16* dsts[7] = {hb, Wqb, Wkb, Wvb, Wob, W1b, W2b};
  int cum = 0;
  for (int t = 0; t < 7; ++t) {
    ca.src[t] = (const float*)d_in[srcIdx[t]];
    ca.dst[t] = dsts[t];
    ca.cum[t] = cum;
    cum += in_sizes[srcIdx[t]] / 8;
  }
  ca.cum[7] = cum;

  const dim3 blk(256);

  // 1. prep: packmask (65536 blocks) + cast
  k_prep<<<dim3(65536 + (cum + 255) / 256), blk, 0, stream>>>(adj, mbits, ca, cum);
  // 2. fused QKV (768 blocks); V blocks write vt directly
  k_gemm_qkv<<<dim3(64, 12), blk, 0, stream>>>(hb, Wqb, bq, bk, bv, q, k, vt);
  // 3. flash attention, split-K x4 (1024 blocks) + combine
  k_attn<<<dim3(1024), blk, 0, stream>>>(q, k, vt, mbits, Opart, Lpart);
  k_attn_combine<<<dim3(1024), blk, 0, stream>>>(Opart, Lpart, ctx);
  // 4. output projection split-K x2 (512 blocks) -> fused combine+LN1 -> h1
  k_gemm_sk<<<dim3(64, 4, 2), blk, 0, stream>>>(ctx, Wob, skP, 512, 512, 256);
  k_addln_sk<0><<<dim3(1024), blk, 0, stream>>>(hb, skP, bo, g1, be1, (void*)h1);
  // 5. ff1 = relu(h1 @ W1^T + b1)  (512 blocks)
  k_gemm<<<dim3(32, 16), blk, 0, stream>>>(h1, W1b, b1, ff1, 2048, 512, 1);
  // 6. ff2 split-K x2 (512 blocks) -> fused combine+LN2 -> d_out (fp32)
  k_gemm_sk<<<dim3(64, 4, 2), blk, 0, stream>>>(ff1, W2b, skP, 512, 2048, 1024);
  k_addln_sk<1><<<dim3(1024), blk, 0, stream>>>(h1, skP, b2, g2, be2, d_out);
}